// Round 10
// baseline (285.109 us; speedup 1.0000x reference)
//
#include <hip/hip_runtime.h>
#include <hip/hip_bf16.h>

// GCN encoder: x = emb[types]; x1 = relu(gcnconv(x,W1,b1)); out = gcnconv(x1,W2,b2)
// gcnconv: deg[i] = indeg(i)+1 (self loop); dis = rsqrt(deg);
//          out[i] = sum_{e:dst=i} (x[src_e]@W)*dis[src]*dis[i] + (x[i]@W)*dis[i]^2 + b
//
// Strategy (round 10):
//  - Bucketed CSR build; csr_p = {src|type<<17, premultiplied coef} (int2).
//  - agg kernels: ONE NODE PER 16-LANE SUB (4 nodes/wave). Zero cross-lane ops
//    (shfl = ds_bpermute was serializing the per-CU DS pipe). Edge payloads
//    read sub-uniform (L1 broadcast); feature rows gathered 16-lane-wide.
//  - embW bf16 (256KB L2-resident): layer-1 gather = 256B/edge = 16 x ushort8.
//  - gemm2: MFMA 16x16x32 bf16 split-hi/lo fp32 emulation; h2 stored bf16.

#define D1 128
#define D2 64
#define BSH 9            // bucket covers 512 nodes
#define BW  512
#define BMAX 256         // max buckets supported (n <= 131072)
#define TILE 2048        // edges per bpart block (8 per thread)
#define SMASK 0x1FFFF    // low 17 bits = src index (n < 131072)

typedef __attribute__((ext_vector_type(8))) short short8v;
typedef __attribute__((ext_vector_type(8))) unsigned short ushort8v;
typedef __attribute__((ext_vector_type(4))) float f32x4;

__device__ __forceinline__ short bf16_hi(float x) {
    return (short)(__float_as_uint(x) >> 16);
}
__device__ __forceinline__ float hi_f(float x) {
    return __uint_as_float(__float_as_uint(x) & 0xFFFF0000u);
}
__device__ __forceinline__ short bf16_rne(float x) {
    unsigned u = __float_as_uint(x);
    return (short)((u + 0x7FFFu + ((u >> 16) & 1u)) >> 16);
}
__device__ __forceinline__ float bf16_f(unsigned short u) {
    return __uint_as_float((unsigned)u << 16);
}

// ---- bucket histogram (LDS-aggregated) ----
__global__ __launch_bounds__(256) void bhist_k(const int* __restrict__ dst,
                                               int* __restrict__ bcnt, int e) {
    __shared__ int h[BMAX];
    if (threadIdx.x < BMAX) h[threadIdx.x] = 0;
    __syncthreads();
    int stride = gridDim.x * blockDim.x;
    for (int t = blockIdx.x * blockDim.x + threadIdx.x; t < e; t += stride)
        atomicAdd(&h[dst[t] >> BSH], 1);
    __syncthreads();
    if (threadIdx.x < BMAX && h[threadIdx.x])
        atomicAdd(&bcnt[threadIdx.x], h[threadIdx.x]);
}

// ---- bucket base scan (one block) ----
__global__ void bscan_k(const int* __restrict__ bcnt, int* __restrict__ bbase,
                        int* __restrict__ bcur, int nb) {
    __shared__ int tmp[BMAX];
    int tid = threadIdx.x;          // 256 threads
    int v = (tid < nb) ? bcnt[tid] : 0;
    tmp[tid] = v;
    __syncthreads();
    for (int s = 1; s < BMAX; s <<= 1) {
        int a = (tid >= s) ? tmp[tid - s] : 0;
        __syncthreads();
        tmp[tid] += a;
        __syncthreads();
    }
    if (tid < nb) { int ex = tmp[tid] - v; bbase[tid] = ex; bcur[tid] = ex; }
}

// ---- partition edges into bucket regions (packed uint: src | dlocal<<17) ----
__global__ __launch_bounds__(256) void bpart_k(const int* __restrict__ src,
                                               const int* __restrict__ dst,
                                               int* __restrict__ bcur,
                                               unsigned* __restrict__ ebuf, int e) {
    __shared__ int hist[BMAX];
    __shared__ int chunk[BMAX];
    __shared__ int lcur[BMAX];
    int tid = threadIdx.x;
    int base = blockIdx.x * TILE;
    if (tid < BMAX) { hist[tid] = 0; lcur[tid] = 0; }
    __syncthreads();
    unsigned p8[8];
    int b8[8];
    #pragma unroll
    for (int i = 0; i < 8; ++i) {
        int t = base + i * 256 + tid;
        if (t < e) {
            int s = src[t], d = dst[t];
            b8[i] = d >> BSH;
            p8[i] = (unsigned)s | ((unsigned)(d & (BW - 1)) << 17);
            atomicAdd(&hist[b8[i]], 1);
        } else b8[i] = -1;
    }
    __syncthreads();
    if (tid < BMAX && hist[tid]) chunk[tid] = atomicAdd(&bcur[tid], hist[tid]);
    __syncthreads();
    #pragma unroll
    for (int i = 0; i < 8; ++i) {
        if (b8[i] >= 0) {
            int r = atomicAdd(&lcur[b8[i]], 1);
            ebuf[chunk[b8[i]] + r] = p8[i];
        }
    }
}

// ---- per-bucket count: cnt/off/dis (dis = rsqrt(indeg+1) born with cnt) ----
__global__ __launch_bounds__(512) void bcsr_count_k(const unsigned* __restrict__ ebuf,
                                                    const int* __restrict__ bbase,
                                                    const int* __restrict__ bcnt,
                                                    int* __restrict__ cnt,
                                                    int* __restrict__ off,
                                                    float* __restrict__ dis, int n) {
    __shared__ int lcnt[BW];
    __shared__ int lsc[BW];
    int b = blockIdx.x;
    int d0 = b << BSH;
    int tid = threadIdx.x;
    lcnt[tid] = 0;
    __syncthreads();
    int ebase = bbase[b], ecnt = bcnt[b];
    for (int t = tid; t < ecnt; t += BW)
        atomicAdd(&lcnt[ebuf[ebase + t] >> 17], 1);
    __syncthreads();
    int v = lcnt[tid];
    lsc[tid] = v;
    __syncthreads();
    for (int s = 1; s < BW; s <<= 1) {
        int a = (tid >= s) ? lsc[tid - s] : 0;
        __syncthreads();
        lsc[tid] += a;
        __syncthreads();
    }
    int node = d0 + tid;
    if (node < n) {
        cnt[node] = v;
        off[node] = ebase + lsc[tid] - v;
        dis[node] = rsqrtf((float)(v + 1));
    }
}

// ---- per-bucket fill: csr_p = {src | type<<17, coef = dis[dst]*dis[src]} ----
__global__ __launch_bounds__(512) void bcsr_fill_k(const unsigned* __restrict__ ebuf,
                                                   const int* __restrict__ bbase,
                                                   const int* __restrict__ bcnt,
                                                   const int* __restrict__ off,
                                                   const float* __restrict__ dis,
                                                   const int* __restrict__ types,
                                                   int2* __restrict__ csr_p, int n) {
    __shared__ int loff[BW];
    __shared__ float ldis[BW];
    __shared__ int lcur[BW];
    int b = blockIdx.x;
    int d0 = b << BSH;
    int tid = threadIdx.x;
    int node = d0 + tid;
    lcur[tid] = 0;
    if (node < n) { loff[tid] = off[node]; ldis[tid] = dis[node]; }
    __syncthreads();
    int ebase = bbase[b], ecnt = bcnt[b];
    for (int t = tid; t < ecnt; t += BW) {
        unsigned q = ebuf[ebase + t];
        int l = q >> 17;
        int s = q & SMASK;
        int r = atomicAdd(&lcur[l], 1);
        float coef = ldis[l] * dis[s];
        csr_p[loff[l] + r] = make_int2(s | (types[s] << 17), __float_as_int(coef));
    }
}

// ---- W2 -> frag-ordered bf16 hi/lo tables ----
__global__ void w2prep_k(const float* __restrict__ W2,
                         short* __restrict__ w2h, short* __restrict__ w2l) {
    int t = blockIdx.x * blockDim.x + threadIdx.x;   // t = k*64 + c
    if (t >= D1 * D2) return;
    int k = t >> 6, c = t & 63;
    float v = W2[t];
    int ct = c >> 4, kb = k >> 5;
    int l = (((k >> 3) & 3) << 4) | (c & 15);
    int j = k & 7;
    int idx = (((ct << 2) | kb) * 64 + l) * 8 + j;
    w2h[idx] = bf16_hi(v);
    w2l[idx] = bf16_rne(v - hi_f(v));
}

// embWb[r][j] = bf16( sum_k emb[r][k] * W1[k][j] )   (ntypes x 128, 256B rows)
__global__ __launch_bounds__(128) void gemm_emb_k(const float* __restrict__ emb,
                                                  const float* __restrict__ W1,
                                                  unsigned short* __restrict__ embWb,
                                                  int ntypes) {
    __shared__ float w[D1 * D1];  // 64 KB
    for (int t = threadIdx.x; t < D1 * D1; t += 128) w[t] = W1[t];
    __syncthreads();
    int j = threadIdx.x;
    for (int r = blockIdx.x; r < ntypes; r += gridDim.x) {
        const float* er = emb + (size_t)r * D1;
        float acc = 0.f;
        #pragma unroll 8
        for (int k = 0; k < D1; ++k) acc = fmaf(er[k], w[k * D1 + j], acc);
        embWb[(size_t)r * D1 + j] = (unsigned short)bf16_rne(acc);
    }
}

// layer-1 aggregation: ONE NODE PER 16-LANE SUB (4 nodes/wave). Lane holds
// features sl*8..sl*8+7. Edge payload read sub-uniform; bf16 row gathers.
// Zero cross-lane ops. Unroll x2, 4 accumulators.
__global__ __launch_bounds__(256) void agg1_k(const int* __restrict__ types,
                                              const int2* __restrict__ csr_p,
                                              const int* __restrict__ off,
                                              const int* __restrict__ cnt,
                                              const float* __restrict__ dis,
                                              const unsigned short* __restrict__ embWb,
                                              const float* __restrict__ b1,
                                              float* __restrict__ x1, int n) {
    int gw = (blockIdx.x * blockDim.x + threadIdx.x) >> 6;  // wave id
    int lane = threadIdx.x & 63;
    int sub = lane >> 4;
    int sl = lane & 15;
    int i = gw * 4 + sub;                 // node owned by this sub
    bool ok = i < n;
    int ii = ok ? i : 0;
    float disi = dis[ii];
    int base = off[ii];
    int c = ok ? cnt[ii] : -1;
    int total = c + 1;                    // self loop at idx==c; ok=false -> 0
    int ti = types[ii];
    float4 a0 = make_float4(0.f, 0.f, 0.f, 0.f);
    float4 a1 = a0, a2 = a0, a3 = a0;
    const unsigned short* ewb = embWb + (sl << 3);
    for (int k0 = 0;; k0 += 2) {
        bool act0 = k0 < total;
        if (!__any(act0)) break;
        bool act1 = k0 + 1 < total;
        int tp0 = 0, tp1 = 0;
        float c0 = 0.f, c1 = 0.f;
        if (act0) {
            if (k0 < c) { int2 q = csr_p[base + k0]; tp0 = q.x >> 17; c0 = __int_as_float(q.y); }
            else        { tp0 = ti; c0 = disi * disi; }
        }
        if (act1) {
            if (k0 + 1 < c) { int2 q = csr_p[base + k0 + 1]; tp1 = q.x >> 17; c1 = __int_as_float(q.y); }
            else            { tp1 = ti; c1 = disi * disi; }
        }
        ushort8v r0 = *(const ushort8v*)(ewb + (size_t)tp0 * D1);
        ushort8v r1 = *(const ushort8v*)(ewb + (size_t)tp1 * D1);
        a0.x = fmaf(bf16_f(r0[0]), c0, a0.x); a0.y = fmaf(bf16_f(r0[1]), c0, a0.y);
        a0.z = fmaf(bf16_f(r0[2]), c0, a0.z); a0.w = fmaf(bf16_f(r0[3]), c0, a0.w);
        a1.x = fmaf(bf16_f(r0[4]), c0, a1.x); a1.y = fmaf(bf16_f(r0[5]), c0, a1.y);
        a1.z = fmaf(bf16_f(r0[6]), c0, a1.z); a1.w = fmaf(bf16_f(r0[7]), c0, a1.w);
        a2.x = fmaf(bf16_f(r1[0]), c1, a2.x); a2.y = fmaf(bf16_f(r1[1]), c1, a2.y);
        a2.z = fmaf(bf16_f(r1[2]), c1, a2.z); a2.w = fmaf(bf16_f(r1[3]), c1, a2.w);
        a3.x = fmaf(bf16_f(r1[4]), c1, a3.x); a3.y = fmaf(bf16_f(r1[5]), c1, a3.y);
        a3.z = fmaf(bf16_f(r1[6]), c1, a3.z); a3.w = fmaf(bf16_f(r1[7]), c1, a3.w);
    }
    if (ok) {
        float4 f0 = make_float4(a0.x + a2.x, a0.y + a2.y, a0.z + a2.z, a0.w + a2.w);
        float4 f1 = make_float4(a1.x + a3.x, a1.y + a3.y, a1.z + a3.z, a1.w + a3.w);
        float4 bv0 = ((const float4*)b1)[sl * 2];
        float4 bv1 = ((const float4*)b1)[sl * 2 + 1];
        f0.x = fmaxf(f0.x + bv0.x, 0.f); f0.y = fmaxf(f0.y + bv0.y, 0.f);
        f0.z = fmaxf(f0.z + bv0.z, 0.f); f0.w = fmaxf(f0.w + bv0.w, 0.f);
        f1.x = fmaxf(f1.x + bv1.x, 0.f); f1.y = fmaxf(f1.y + bv1.y, 0.f);
        f1.z = fmaxf(f1.z + bv1.z, 0.f); f1.w = fmaxf(f1.w + bv1.w, 0.f);
        ((float4*)(x1 + (size_t)i * D1))[sl * 2] = f0;
        ((float4*)(x1 + (size_t)i * D1))[sl * 2 + 1] = f1;
    }
}

// h2 = x1 @ W2 via MFMA -> BF16 dense [n][64].
// One wave per 16 rows. Split-bf16 fp32 emulation: xh@Wh + xl@Wh + xh@Wl.
__global__ __launch_bounds__(256) void gemm2_k(const float* __restrict__ x1,
                                               const short* __restrict__ w2h,
                                               const short* __restrict__ w2l,
                                               unsigned short* __restrict__ h2b, int n) {
    int gw = (blockIdx.x * blockDim.x + threadIdx.x) >> 6;  // global wave id
    int lane = threadIdx.x & 63;
    int r0 = gw << 4;
    if (r0 >= n) return;
    int row = r0 + (lane & 15);
    int kq = lane >> 4;             // 0..3
    bool ok = row < n;
    const float* xr = x1 + (size_t)row * D1 + kq * 8;
    short8v ah[4], al[4];
    #pragma unroll
    for (int kb = 0; kb < 4; ++kb) {
        float4 v0, v1;
        if (ok) {
            v0 = *(const float4*)(xr + kb * 32);
            v1 = *(const float4*)(xr + kb * 32 + 4);
        } else {
            v0 = make_float4(0.f, 0.f, 0.f, 0.f);
            v1 = v0;
        }
        float xv[8] = {v0.x, v0.y, v0.z, v0.w, v1.x, v1.y, v1.z, v1.w};
        #pragma unroll
        for (int j = 0; j < 8; ++j) {
            ah[kb][j] = bf16_hi(xv[j]);
            al[kb][j] = bf16_rne(xv[j] - hi_f(xv[j]));
        }
    }
    const short8v* w2hv = (const short8v*)w2h;
    const short8v* w2lv = (const short8v*)w2l;
    #pragma unroll
    for (int ct = 0; ct < 4; ++ct) {
        f32x4 acc = {0.f, 0.f, 0.f, 0.f};
        #pragma unroll
        for (int kb = 0; kb < 4; ++kb) {
            short8v bh = w2hv[(ct * 4 + kb) * 64 + lane];
            short8v bl = w2lv[(ct * 4 + kb) * 64 + lane];
            acc = __builtin_amdgcn_mfma_f32_16x16x32_bf16(ah[kb], bh, acc, 0, 0, 0);
            acc = __builtin_amdgcn_mfma_f32_16x16x32_bf16(al[kb], bh, acc, 0, 0, 0);
            acc = __builtin_amdgcn_mfma_f32_16x16x32_bf16(ah[kb], bl, acc, 0, 0, 0);
        }
        #pragma unroll
        for (int v = 0; v < 4; ++v) {
            int orow = r0 + (lane >> 4) * 4 + v;
            if (orow < n)
                h2b[(size_t)orow * D2 + ct * 16 + (lane & 15)] =
                    (unsigned short)bf16_rne(acc[v]);
        }
    }
}

// layer-2 aggregation: ONE NODE PER 16-LANE SUB (4 nodes/wave). Lane holds
// features sl*4..sl*4+3 (bf16 h2 rows, 128B). Zero cross-lane ops. Unroll x2.
__global__ __launch_bounds__(256) void agg2_k(const int2* __restrict__ csr_p,
                                              const int* __restrict__ off,
                                              const int* __restrict__ cnt,
                                              const float* __restrict__ dis,
                                              const unsigned short* __restrict__ h2b,
                                              const float* __restrict__ b2,
                                              float* __restrict__ out, int n) {
    int gw = (blockIdx.x * blockDim.x + threadIdx.x) >> 6;  // wave id
    int lane = threadIdx.x & 63;
    int sub = lane >> 4;
    int sl = lane & 15;
    int i = gw * 4 + sub;                 // node owned by this sub
    bool ok = i < n;
    int ii = ok ? i : 0;
    float disi = dis[ii];
    int base = off[ii];
    int c = ok ? cnt[ii] : -1;
    int total = c + 1;                    // self loop at idx==c; ok=false -> 0
    float4 a0 = make_float4(0.f, 0.f, 0.f, 0.f);
    float4 a1 = a0;
    const unsigned short* hb = h2b + (sl << 2);
    for (int k0 = 0;; k0 += 2) {
        bool act0 = k0 < total;
        if (!__any(act0)) break;
        bool act1 = k0 + 1 < total;
        int s0 = 0, s1 = 0;
        float c0 = 0.f, c1 = 0.f;
        if (act0) {
            if (k0 < c) { int2 q = csr_p[base + k0]; s0 = q.x & SMASK; c0 = __int_as_float(q.y); }
            else        { s0 = ii; c0 = disi * disi; }
        }
        if (act1) {
            if (k0 + 1 < c) { int2 q = csr_p[base + k0 + 1]; s1 = q.x & SMASK; c1 = __int_as_float(q.y); }
            else            { s1 = ii; c1 = disi * disi; }
        }
        ushort4 r0 = *(const ushort4*)(hb + (size_t)s0 * D2);
        ushort4 r1 = *(const ushort4*)(hb + (size_t)s1 * D2);
        a0.x = fmaf(bf16_f(r0.x), c0, a0.x); a0.y = fmaf(bf16_f(r0.y), c0, a0.y);
        a0.z = fmaf(bf16_f(r0.z), c0, a0.z); a0.w = fmaf(bf16_f(r0.w), c0, a0.w);
        a1.x = fmaf(bf16_f(r1.x), c1, a1.x); a1.y = fmaf(bf16_f(r1.y), c1, a1.y);
        a1.z = fmaf(bf16_f(r1.z), c1, a1.z); a1.w = fmaf(bf16_f(r1.w), c1, a1.w);
    }
    if (ok) {
        float4 bv = ((const float4*)b2)[sl];
        float4 f;
        f.x = a0.x + a1.x + bv.x;
        f.y = a0.y + a1.y + bv.y;
        f.z = a0.z + a1.z + bv.z;
        f.w = a0.w + a1.w + bv.w;
        ((float4*)(out + (size_t)i * D2))[sl] = f;
    }
}

extern "C" void kernel_launch(void* const* d_in, const int* in_sizes, int n_in,
                              void* d_out, int out_size, void* d_ws, size_t ws_size,
                              hipStream_t stream) {
    const int* types = (const int*)d_in[0];
    const int* edges = (const int*)d_in[1];
    const float* emb = (const float*)d_in[2];
    const float* W1  = (const float*)d_in[3];
    const float* b1  = (const float*)d_in[4];
    const float* W2  = (const float*)d_in[5];
    const float* b2  = (const float*)d_in[6];
    float* out = (float*)d_out;

    const int n = in_sizes[0];
    const int e = in_sizes[1] / 2;
    const int ntypes = in_sizes[2] / D1;
    const int* src = edges;
    const int* dst = edges + e;
    const int nb = (n + BW - 1) >> BSH;   // 196 buckets for n=100000 (<= BMAX)

    // ---- workspace layout (256B aligned slabs) ----
    char* p = (char*)d_ws;
    auto alloc = [&](size_t bytes) {
        char* r = p;
        p += (bytes + 255) & ~(size_t)255;
        return r;
    };
    int*      bcnt  = (int*)      alloc(BMAX * 4);
    int*      bbase = (int*)      alloc(BMAX * 4);
    int*      bcur  = (int*)      alloc(BMAX * 4);
    int*      cnt   = (int*)      alloc((size_t)n * 4);
    int*      off   = (int*)      alloc((size_t)n * 4);
    float*    dis   = (float*)    alloc((size_t)n * 4);
    short*    w2h   = (short*)    alloc((size_t)D1 * D2 * 2);
    short*    w2l   = (short*)    alloc((size_t)D1 * D2 * 2);
    unsigned* ebuf  = (unsigned*) alloc((size_t)e * 4);
    int2*     csr_p = (int2*)     alloc((size_t)e * 8);
    unsigned short* embWb = (unsigned short*)alloc((size_t)ntypes * D1 * 2);
    float*    x1    = (float*)    alloc((size_t)n * D1 * 4);
    unsigned short* h2b = (unsigned short*)alloc((size_t)n * D2 * 2);
    (void)ws_size;

    hipMemsetAsync(bcnt, 0, BMAX * 4, stream);

    // ---- bucketed CSR build ----
    bhist_k<<<512, 256, 0, stream>>>(dst, bcnt, e);
    bscan_k<<<1, BMAX, 0, stream>>>(bcnt, bbase, bcur, nb);
    bpart_k<<<(e + TILE - 1) / TILE, 256, 0, stream>>>(src, dst, bcur, ebuf, e);
    bcsr_count_k<<<nb, BW, 0, stream>>>(ebuf, bbase, bcnt, cnt, off, dis, n);
    bcsr_fill_k<<<nb, BW, 0, stream>>>(ebuf, bbase, bcnt, off, dis, types, csr_p, n);
    w2prep_k<<<(D1 * D2 + 255) / 256, 256, 0, stream>>>(W2, w2h, w2l);

    // ---- layer 1: embWb = bf16(emb@W1); aggregate -> x1 (relu(agg + b1)) ----
    gemm_emb_k<<<256, 128, 0, stream>>>(emb, W1, embWb, ntypes);
    int ngrid = (n + 15) / 16;  // 4 waves/block x 4 nodes/wave
    agg1_k<<<ngrid, 256, 0, stream>>>(types, csr_p, off, cnt, dis, embWb, b1, x1, n);

    // ---- layer 2: h2 = x1@W2 (MFMA -> bf16); aggregate h2 -> out ----
    int ngw = (n + 15) / 16;
    gemm2_k<<<(ngw + 3) / 4, 256, 0, stream>>>(x1, w2h, w2l, h2b, n);
    agg2_k<<<ngrid, 256, 0, stream>>>(csr_p, off, cnt, dis, h2b, b2, out, n);
}

// Round 11
// 269.155 us; speedup vs baseline: 1.0593x; 1.0593x over previous
//
#include <hip/hip_runtime.h>
#include <hip/hip_bf16.h>

// GCN encoder: x = emb[types]; x1 = relu(gcnconv(x,W1,b1)); out = gcnconv(x1,W2,b2)
// gcnconv: deg[i] = indeg(i)+1 (self loop); dis = rsqrt(deg);
//          out[i] = sum_{e:dst=i} (x[src_e]@W)*dis[src]*dis[i] + (x[i]@W)*dis[i]^2 + b
//
// Strategy (round 11):
//  - Bucketed CSR build; csr_p = {src|type<<17, premultiplied coef} (int2).
//  - agg kernels: ONE NODE PER 16-LANE SUB, zero cross-lane ops, and a
//    SOFTWARE-PIPELINED edge loop: 4 payloads double-buffered (prefetch next 4
//    before consuming current 4) + 4 independent row gathers in flight.
//    Self-loop hoisted out; tail via clamped index + zero coef (no votes).
//  - embW bf16 (256KB L2-resident); h2 bf16 (12.8MB).
//  - gemm2: MFMA 16x16x32 bf16 split-hi/lo fp32 emulation.

#define D1 128
#define D2 64
#define BSH 9            // bucket covers 512 nodes
#define BW  512
#define BMAX 256         // max buckets supported (n <= 131072)
#define TILE 2048        // edges per bpart block (8 per thread)
#define SMASK 0x1FFFF    // low 17 bits = src index (n < 131072)

typedef __attribute__((ext_vector_type(8))) short short8v;
typedef __attribute__((ext_vector_type(8))) unsigned short ushort8v;
typedef __attribute__((ext_vector_type(4))) float f32x4;

__device__ __forceinline__ short bf16_hi(float x) {
    return (short)(__float_as_uint(x) >> 16);
}
__device__ __forceinline__ float hi_f(float x) {
    return __uint_as_float(__float_as_uint(x) & 0xFFFF0000u);
}
__device__ __forceinline__ short bf16_rne(float x) {
    unsigned u = __float_as_uint(x);
    return (short)((u + 0x7FFFu + ((u >> 16) & 1u)) >> 16);
}
__device__ __forceinline__ float bf16_f(unsigned short u) {
    return __uint_as_float((unsigned)u << 16);
}

// ---- bucket histogram (LDS-aggregated) ----
__global__ __launch_bounds__(256) void bhist_k(const int* __restrict__ dst,
                                               int* __restrict__ bcnt, int e) {
    __shared__ int h[BMAX];
    if (threadIdx.x < BMAX) h[threadIdx.x] = 0;
    __syncthreads();
    int stride = gridDim.x * blockDim.x;
    for (int t = blockIdx.x * blockDim.x + threadIdx.x; t < e; t += stride)
        atomicAdd(&h[dst[t] >> BSH], 1);
    __syncthreads();
    if (threadIdx.x < BMAX && h[threadIdx.x])
        atomicAdd(&bcnt[threadIdx.x], h[threadIdx.x]);
}

// ---- bucket base scan (one block) ----
__global__ void bscan_k(const int* __restrict__ bcnt, int* __restrict__ bbase,
                        int* __restrict__ bcur, int nb) {
    __shared__ int tmp[BMAX];
    int tid = threadIdx.x;          // 256 threads
    int v = (tid < nb) ? bcnt[tid] : 0;
    tmp[tid] = v;
    __syncthreads();
    for (int s = 1; s < BMAX; s <<= 1) {
        int a = (tid >= s) ? tmp[tid - s] : 0;
        __syncthreads();
        tmp[tid] += a;
        __syncthreads();
    }
    if (tid < nb) { int ex = tmp[tid] - v; bbase[tid] = ex; bcur[tid] = ex; }
}

// ---- partition edges into bucket regions (packed uint: src | dlocal<<17) ----
__global__ __launch_bounds__(256) void bpart_k(const int* __restrict__ src,
                                               const int* __restrict__ dst,
                                               int* __restrict__ bcur,
                                               unsigned* __restrict__ ebuf, int e) {
    __shared__ int hist[BMAX];
    __shared__ int chunk[BMAX];
    __shared__ int lcur[BMAX];
    int tid = threadIdx.x;
    int base = blockIdx.x * TILE;
    if (tid < BMAX) { hist[tid] = 0; lcur[tid] = 0; }
    __syncthreads();
    unsigned p8[8];
    int b8[8];
    #pragma unroll
    for (int i = 0; i < 8; ++i) {
        int t = base + i * 256 + tid;
        if (t < e) {
            int s = src[t], d = dst[t];
            b8[i] = d >> BSH;
            p8[i] = (unsigned)s | ((unsigned)(d & (BW - 1)) << 17);
            atomicAdd(&hist[b8[i]], 1);
        } else b8[i] = -1;
    }
    __syncthreads();
    if (tid < BMAX && hist[tid]) chunk[tid] = atomicAdd(&bcur[tid], hist[tid]);
    __syncthreads();
    #pragma unroll
    for (int i = 0; i < 8; ++i) {
        if (b8[i] >= 0) {
            int r = atomicAdd(&lcur[b8[i]], 1);
            ebuf[chunk[b8[i]] + r] = p8[i];
        }
    }
}

// ---- per-bucket count: cnt/off/dis (dis = rsqrt(indeg+1) born with cnt) ----
__global__ __launch_bounds__(512) void bcsr_count_k(const unsigned* __restrict__ ebuf,
                                                    const int* __restrict__ bbase,
                                                    const int* __restrict__ bcnt,
                                                    int* __restrict__ cnt,
                                                    int* __restrict__ off,
                                                    float* __restrict__ dis, int n) {
    __shared__ int lcnt[BW];
    __shared__ int lsc[BW];
    int b = blockIdx.x;
    int d0 = b << BSH;
    int tid = threadIdx.x;
    lcnt[tid] = 0;
    __syncthreads();
    int ebase = bbase[b], ecnt = bcnt[b];
    for (int t = tid; t < ecnt; t += BW)
        atomicAdd(&lcnt[ebuf[ebase + t] >> 17], 1);
    __syncthreads();
    int v = lcnt[tid];
    lsc[tid] = v;
    __syncthreads();
    for (int s = 1; s < BW; s <<= 1) {
        int a = (tid >= s) ? lsc[tid - s] : 0;
        __syncthreads();
        lsc[tid] += a;
        __syncthreads();
    }
    int node = d0 + tid;
    if (node < n) {
        cnt[node] = v;
        off[node] = ebase + lsc[tid] - v;
        dis[node] = rsqrtf((float)(v + 1));
    }
}

// ---- per-bucket fill: csr_p = {src | type<<17, coef = dis[dst]*dis[src]} ----
__global__ __launch_bounds__(512) void bcsr_fill_k(const unsigned* __restrict__ ebuf,
                                                   const int* __restrict__ bbase,
                                                   const int* __restrict__ bcnt,
                                                   const int* __restrict__ off,
                                                   const float* __restrict__ dis,
                                                   const int* __restrict__ types,
                                                   int2* __restrict__ csr_p, int n) {
    __shared__ int loff[BW];
    __shared__ float ldis[BW];
    __shared__ int lcur[BW];
    int b = blockIdx.x;
    int d0 = b << BSH;
    int tid = threadIdx.x;
    int node = d0 + tid;
    lcur[tid] = 0;
    if (node < n) { loff[tid] = off[node]; ldis[tid] = dis[node]; }
    __syncthreads();
    int ebase = bbase[b], ecnt = bcnt[b];
    for (int t = tid; t < ecnt; t += BW) {
        unsigned q = ebuf[ebase + t];
        int l = q >> 17;
        int s = q & SMASK;
        int r = atomicAdd(&lcur[l], 1);
        float coef = ldis[l] * dis[s];
        csr_p[loff[l] + r] = make_int2(s | (types[s] << 17), __float_as_int(coef));
    }
}

// ---- W2 -> frag-ordered bf16 hi/lo tables ----
__global__ void w2prep_k(const float* __restrict__ W2,
                         short* __restrict__ w2h, short* __restrict__ w2l) {
    int t = blockIdx.x * blockDim.x + threadIdx.x;   // t = k*64 + c
    if (t >= D1 * D2) return;
    int k = t >> 6, c = t & 63;
    float v = W2[t];
    int ct = c >> 4, kb = k >> 5;
    int l = (((k >> 3) & 3) << 4) | (c & 15);
    int j = k & 7;
    int idx = (((ct << 2) | kb) * 64 + l) * 8 + j;
    w2h[idx] = bf16_hi(v);
    w2l[idx] = bf16_rne(v - hi_f(v));
}

// embWb[r][j] = bf16( sum_k emb[r][k] * W1[k][j] )   (ntypes x 128, 256B rows)
__global__ __launch_bounds__(128) void gemm_emb_k(const float* __restrict__ emb,
                                                  const float* __restrict__ W1,
                                                  unsigned short* __restrict__ embWb,
                                                  int ntypes) {
    __shared__ float w[D1 * D1];  // 64 KB
    for (int t = threadIdx.x; t < D1 * D1; t += 128) w[t] = W1[t];
    __syncthreads();
    int j = threadIdx.x;
    for (int r = blockIdx.x; r < ntypes; r += gridDim.x) {
        const float* er = emb + (size_t)r * D1;
        float acc = 0.f;
        #pragma unroll 8
        for (int k = 0; k < D1; ++k) acc = fmaf(er[k], w[k * D1 + j], acc);
        embWb[(size_t)r * D1 + j] = (unsigned short)bf16_rne(acc);
    }
}

// layer-1 aggregation: ONE NODE PER 16-LANE SUB; software-pipelined edge loop:
// double-buffered payload quad + 4 independent 16B row gathers in flight.
__global__ __launch_bounds__(256) void agg1_k(const int* __restrict__ types,
                                              const int2* __restrict__ csr_p,
                                              const int* __restrict__ off,
                                              const int* __restrict__ cnt,
                                              const float* __restrict__ dis,
                                              const unsigned short* __restrict__ embWb,
                                              const float* __restrict__ b1,
                                              float* __restrict__ x1, int n) {
    int gw = (blockIdx.x * blockDim.x + threadIdx.x) >> 6;  // wave id
    int lane = threadIdx.x & 63;
    int sub = lane >> 4;
    int sl = lane & 15;
    int i = gw * 4 + sub;                 // node owned by this sub
    bool ok = i < n;
    int ii = ok ? i : 0;
    float disi = dis[ii];
    int base = off[ii];
    int c = ok ? cnt[ii] : 0;
    const unsigned short* ewb = embWb + (sl << 3);
    float4 a0, a1, a2, a3;
    {   // self loop: coef = 1/deg
        float cf = disi * disi;
        ushort8v r = *(const ushort8v*)(ewb + (size_t)types[ii] * D1);
        a0.x = bf16_f(r[0]) * cf; a0.y = bf16_f(r[1]) * cf;
        a0.z = bf16_f(r[2]) * cf; a0.w = bf16_f(r[3]) * cf;
        a1.x = bf16_f(r[4]) * cf; a1.y = bf16_f(r[5]) * cf;
        a1.z = bf16_f(r[6]) * cf; a1.w = bf16_f(r[7]) * cf;
    }
    a2 = make_float4(0.f, 0.f, 0.f, 0.f);
    a3 = a2;
    if (c > 0) {
        int cm = c - 1;
        int2 p0 = csr_p[base];
        int2 p1 = csr_p[base + min(1, cm)];
        int2 p2 = csr_p[base + min(2, cm)];
        int2 p3 = csr_p[base + min(3, cm)];
        for (int k = 0; k < c; k += 4) {
            // prefetch next quad (clamped; hides under this quad's gathers)
            int2 q0 = csr_p[base + min(k + 4, cm)];
            int2 q1 = csr_p[base + min(k + 5, cm)];
            int2 q2 = csr_p[base + min(k + 6, cm)];
            int2 q3 = csr_p[base + min(k + 7, cm)];
            // 4 independent row gathers
            ushort8v r0 = *(const ushort8v*)(ewb + (size_t)(p0.x >> 17) * D1);
            ushort8v r1 = *(const ushort8v*)(ewb + (size_t)(p1.x >> 17) * D1);
            ushort8v r2 = *(const ushort8v*)(ewb + (size_t)(p2.x >> 17) * D1);
            ushort8v r3 = *(const ushort8v*)(ewb + (size_t)(p3.x >> 17) * D1);
            float c0 = __int_as_float(p0.y);                      // k < c always
            float c1 = (k + 1 < c) ? __int_as_float(p1.y) : 0.f;
            float c2 = (k + 2 < c) ? __int_as_float(p2.y) : 0.f;
            float c3 = (k + 3 < c) ? __int_as_float(p3.y) : 0.f;
            a0.x = fmaf(bf16_f(r0[0]), c0, a0.x); a0.y = fmaf(bf16_f(r0[1]), c0, a0.y);
            a0.z = fmaf(bf16_f(r0[2]), c0, a0.z); a0.w = fmaf(bf16_f(r0[3]), c0, a0.w);
            a1.x = fmaf(bf16_f(r0[4]), c0, a1.x); a1.y = fmaf(bf16_f(r0[5]), c0, a1.y);
            a1.z = fmaf(bf16_f(r0[6]), c0, a1.z); a1.w = fmaf(bf16_f(r0[7]), c0, a1.w);
            a2.x = fmaf(bf16_f(r1[0]), c1, a2.x); a2.y = fmaf(bf16_f(r1[1]), c1, a2.y);
            a2.z = fmaf(bf16_f(r1[2]), c1, a2.z); a2.w = fmaf(bf16_f(r1[3]), c1, a2.w);
            a3.x = fmaf(bf16_f(r1[4]), c1, a3.x); a3.y = fmaf(bf16_f(r1[5]), c1, a3.y);
            a3.z = fmaf(bf16_f(r1[6]), c1, a3.z); a3.w = fmaf(bf16_f(r1[7]), c1, a3.w);
            a0.x = fmaf(bf16_f(r2[0]), c2, a0.x); a0.y = fmaf(bf16_f(r2[1]), c2, a0.y);
            a0.z = fmaf(bf16_f(r2[2]), c2, a0.z); a0.w = fmaf(bf16_f(r2[3]), c2, a0.w);
            a1.x = fmaf(bf16_f(r2[4]), c2, a1.x); a1.y = fmaf(bf16_f(r2[5]), c2, a1.y);
            a1.z = fmaf(bf16_f(r2[6]), c2, a1.z); a1.w = fmaf(bf16_f(r2[7]), c2, a1.w);
            a2.x = fmaf(bf16_f(r3[0]), c3, a2.x); a2.y = fmaf(bf16_f(r3[1]), c3, a2.y);
            a2.z = fmaf(bf16_f(r3[2]), c3, a2.z); a2.w = fmaf(bf16_f(r3[3]), c3, a2.w);
            a3.x = fmaf(bf16_f(r3[4]), c3, a3.x); a3.y = fmaf(bf16_f(r3[5]), c3, a3.y);
            a3.z = fmaf(bf16_f(r3[6]), c3, a3.z); a3.w = fmaf(bf16_f(r3[7]), c3, a3.w);
            p0 = q0; p1 = q1; p2 = q2; p3 = q3;
        }
    }
    if (ok) {
        float4 f0 = make_float4(a0.x + a2.x, a0.y + a2.y, a0.z + a2.z, a0.w + a2.w);
        float4 f1 = make_float4(a1.x + a3.x, a1.y + a3.y, a1.z + a3.z, a1.w + a3.w);
        float4 bv0 = ((const float4*)b1)[sl * 2];
        float4 bv1 = ((const float4*)b1)[sl * 2 + 1];
        f0.x = fmaxf(f0.x + bv0.x, 0.f); f0.y = fmaxf(f0.y + bv0.y, 0.f);
        f0.z = fmaxf(f0.z + bv0.z, 0.f); f0.w = fmaxf(f0.w + bv0.w, 0.f);
        f1.x = fmaxf(f1.x + bv1.x, 0.f); f1.y = fmaxf(f1.y + bv1.y, 0.f);
        f1.z = fmaxf(f1.z + bv1.z, 0.f); f1.w = fmaxf(f1.w + bv1.w, 0.f);
        ((float4*)(x1 + (size_t)i * D1))[sl * 2] = f0;
        ((float4*)(x1 + (size_t)i * D1))[sl * 2 + 1] = f1;
    }
}

// h2 = x1 @ W2 via MFMA -> BF16 dense [n][64].
// One wave per 16 rows. Split-bf16 fp32 emulation: xh@Wh + xl@Wh + xh@Wl.
__global__ __launch_bounds__(256) void gemm2_k(const float* __restrict__ x1,
                                               const short* __restrict__ w2h,
                                               const short* __restrict__ w2l,
                                               unsigned short* __restrict__ h2b, int n) {
    int gw = (blockIdx.x * blockDim.x + threadIdx.x) >> 6;  // global wave id
    int lane = threadIdx.x & 63;
    int r0 = gw << 4;
    if (r0 >= n) return;
    int row = r0 + (lane & 15);
    int kq = lane >> 4;             // 0..3
    bool ok = row < n;
    const float* xr = x1 + (size_t)row * D1 + kq * 8;
    short8v ah[4], al[4];
    #pragma unroll
    for (int kb = 0; kb < 4; ++kb) {
        float4 v0, v1;
        if (ok) {
            v0 = *(const float4*)(xr + kb * 32);
            v1 = *(const float4*)(xr + kb * 32 + 4);
        } else {
            v0 = make_float4(0.f, 0.f, 0.f, 0.f);
            v1 = v0;
        }
        float xv[8] = {v0.x, v0.y, v0.z, v0.w, v1.x, v1.y, v1.z, v1.w};
        #pragma unroll
        for (int j = 0; j < 8; ++j) {
            ah[kb][j] = bf16_hi(xv[j]);
            al[kb][j] = bf16_rne(xv[j] - hi_f(xv[j]));
        }
    }
    const short8v* w2hv = (const short8v*)w2h;
    const short8v* w2lv = (const short8v*)w2l;
    #pragma unroll
    for (int ct = 0; ct < 4; ++ct) {
        f32x4 acc = {0.f, 0.f, 0.f, 0.f};
        #pragma unroll
        for (int kb = 0; kb < 4; ++kb) {
            short8v bh = w2hv[(ct * 4 + kb) * 64 + lane];
            short8v bl = w2lv[(ct * 4 + kb) * 64 + lane];
            acc = __builtin_amdgcn_mfma_f32_16x16x32_bf16(ah[kb], bh, acc, 0, 0, 0);
            acc = __builtin_amdgcn_mfma_f32_16x16x32_bf16(al[kb], bh, acc, 0, 0, 0);
            acc = __builtin_amdgcn_mfma_f32_16x16x32_bf16(ah[kb], bl, acc, 0, 0, 0);
        }
        #pragma unroll
        for (int v = 0; v < 4; ++v) {
            int orow = r0 + (lane >> 4) * 4 + v;
            if (orow < n)
                h2b[(size_t)orow * D2 + ct * 16 + (lane & 15)] =
                    (unsigned short)bf16_rne(acc[v]);
        }
    }
}

// layer-2 aggregation: ONE NODE PER 16-LANE SUB; software-pipelined edge loop:
// double-buffered payload quad + 4 independent 8B row gathers in flight.
__global__ __launch_bounds__(256) void agg2_k(const int2* __restrict__ csr_p,
                                              const int* __restrict__ off,
                                              const int* __restrict__ cnt,
                                              const float* __restrict__ dis,
                                              const unsigned short* __restrict__ h2b,
                                              const float* __restrict__ b2,
                                              float* __restrict__ out, int n) {
    int gw = (blockIdx.x * blockDim.x + threadIdx.x) >> 6;  // wave id
    int lane = threadIdx.x & 63;
    int sub = lane >> 4;
    int sl = lane & 15;
    int i = gw * 4 + sub;                 // node owned by this sub
    bool ok = i < n;
    int ii = ok ? i : 0;
    float disi = dis[ii];
    int base = off[ii];
    int c = ok ? cnt[ii] : 0;
    const unsigned short* hb = h2b + (sl << 2);
    float4 a0, a1;
    {   // self loop: coef = 1/deg
        float cf = disi * disi;
        ushort4 r = *(const ushort4*)(hb + (size_t)ii * D2);
        a0.x = bf16_f(r.x) * cf; a0.y = bf16_f(r.y) * cf;
        a0.z = bf16_f(r.z) * cf; a0.w = bf16_f(r.w) * cf;
    }
    a1 = make_float4(0.f, 0.f, 0.f, 0.f);
    if (c > 0) {
        int cm = c - 1;
        int2 p0 = csr_p[base];
        int2 p1 = csr_p[base + min(1, cm)];
        int2 p2 = csr_p[base + min(2, cm)];
        int2 p3 = csr_p[base + min(3, cm)];
        for (int k = 0; k < c; k += 4) {
            int2 q0 = csr_p[base + min(k + 4, cm)];
            int2 q1 = csr_p[base + min(k + 5, cm)];
            int2 q2 = csr_p[base + min(k + 6, cm)];
            int2 q3 = csr_p[base + min(k + 7, cm)];
            ushort4 r0 = *(const ushort4*)(hb + (size_t)(p0.x & SMASK) * D2);
            ushort4 r1 = *(const ushort4*)(hb + (size_t)(p1.x & SMASK) * D2);
            ushort4 r2 = *(const ushort4*)(hb + (size_t)(p2.x & SMASK) * D2);
            ushort4 r3 = *(const ushort4*)(hb + (size_t)(p3.x & SMASK) * D2);
            float c0 = __int_as_float(p0.y);                      // k < c always
            float c1 = (k + 1 < c) ? __int_as_float(p1.y) : 0.f;
            float c2 = (k + 2 < c) ? __int_as_float(p2.y) : 0.f;
            float c3 = (k + 3 < c) ? __int_as_float(p3.y) : 0.f;
            a0.x = fmaf(bf16_f(r0.x), c0, a0.x); a0.y = fmaf(bf16_f(r0.y), c0, a0.y);
            a0.z = fmaf(bf16_f(r0.z), c0, a0.z); a0.w = fmaf(bf16_f(r0.w), c0, a0.w);
            a1.x = fmaf(bf16_f(r1.x), c1, a1.x); a1.y = fmaf(bf16_f(r1.y), c1, a1.y);
            a1.z = fmaf(bf16_f(r1.z), c1, a1.z); a1.w = fmaf(bf16_f(r1.w), c1, a1.w);
            a0.x = fmaf(bf16_f(r2.x), c2, a0.x); a0.y = fmaf(bf16_f(r2.y), c2, a0.y);
            a0.z = fmaf(bf16_f(r2.z), c2, a0.z); a0.w = fmaf(bf16_f(r2.w), c2, a0.w);
            a1.x = fmaf(bf16_f(r3.x), c3, a1.x); a1.y = fmaf(bf16_f(r3.y), c3, a1.y);
            a1.z = fmaf(bf16_f(r3.z), c3, a1.z); a1.w = fmaf(bf16_f(r3.w), c3, a1.w);
            p0 = q0; p1 = q1; p2 = q2; p3 = q3;
        }
    }
    if (ok) {
        float4 bv = ((const float4*)b2)[sl];
        float4 f;
        f.x = a0.x + a1.x + bv.x;
        f.y = a0.y + a1.y + bv.y;
        f.z = a0.z + a1.z + bv.z;
        f.w = a0.w + a1.w + bv.w;
        ((float4*)(out + (size_t)i * D2))[sl] = f;
    }
}

extern "C" void kernel_launch(void* const* d_in, const int* in_sizes, int n_in,
                              void* d_out, int out_size, void* d_ws, size_t ws_size,
                              hipStream_t stream) {
    const int* types = (const int*)d_in[0];
    const int* edges = (const int*)d_in[1];
    const float* emb = (const float*)d_in[2];
    const float* W1  = (const float*)d_in[3];
    const float* b1  = (const float*)d_in[4];
    const float* W2  = (const float*)d_in[5];
    const float* b2  = (const float*)d_in[6];
    float* out = (float*)d_out;

    const int n = in_sizes[0];
    const int e = in_sizes[1] / 2;
    const int ntypes = in_sizes[2] / D1;
    const int* src = edges;
    const int* dst = edges + e;
    const int nb = (n + BW - 1) >> BSH;   // 196 buckets for n=100000 (<= BMAX)

    // ---- workspace layout (256B aligned slabs) ----
    char* p = (char*)d_ws;
    auto alloc = [&](size_t bytes) {
        char* r = p;
        p += (bytes + 255) & ~(size_t)255;
        return r;
    };
    int*      bcnt  = (int*)      alloc(BMAX * 4);
    int*      bbase = (int*)      alloc(BMAX * 4);
    int*      bcur  = (int*)      alloc(BMAX * 4);
    int*      cnt   = (int*)      alloc((size_t)n * 4);
    int*      off   = (int*)      alloc((size_t)n * 4);
    float*    dis   = (float*)    alloc((size_t)n * 4);
    short*    w2h   = (short*)    alloc((size_t)D1 * D2 * 2);
    short*    w2l   = (short*)    alloc((size_t)D1 * D2 * 2);
    unsigned* ebuf  = (unsigned*) alloc((size_t)e * 4);
    int2*     csr_p = (int2*)     alloc((size_t)e * 8);
    unsigned short* embWb = (unsigned short*)alloc((size_t)ntypes * D1 * 2);
    float*    x1    = (float*)    alloc((size_t)n * D1 * 4);
    unsigned short* h2b = (unsigned short*)alloc((size_t)n * D2 * 2);
    (void)ws_size;

    hipMemsetAsync(bcnt, 0, BMAX * 4, stream);

    // ---- bucketed CSR build ----
    bhist_k<<<512, 256, 0, stream>>>(dst, bcnt, e);
    bscan_k<<<1, BMAX, 0, stream>>>(bcnt, bbase, bcur, nb);
    bpart_k<<<(e + TILE - 1) / TILE, 256, 0, stream>>>(src, dst, bcur, ebuf, e);
    bcsr_count_k<<<nb, BW, 0, stream>>>(ebuf, bbase, bcnt, cnt, off, dis, n);
    bcsr_fill_k<<<nb, BW, 0, stream>>>(ebuf, bbase, bcnt, off, dis, types, csr_p, n);
    w2prep_k<<<(D1 * D2 + 255) / 256, 256, 0, stream>>>(W2, w2h, w2l);

    // ---- layer 1: embWb = bf16(emb@W1); aggregate -> x1 (relu(agg + b1)) ----
    gemm_emb_k<<<256, 128, 0, stream>>>(emb, W1, embWb, ntypes);
    int ngrid = (n + 15) / 16;  // 4 waves/block x 4 nodes/wave
    agg1_k<<<ngrid, 256, 0, stream>>>(types, csr_p, off, cnt, dis, embWb, b1, x1, n);

    // ---- layer 2: h2 = x1@W2 (MFMA -> bf16); aggregate h2 -> out ----
    int ngw = (n + 15) / 16;
    gemm2_k<<<(ngw + 3) / 4, 256, 0, stream>>>(x1, w2h, w2l, h2b, n);
    agg2_k<<<ngrid, 256, 0, stream>>>(csr_p, off, cnt, dis, h2b, b2, out, n);
}